// Round 2
// baseline (465.229 us; speedup 1.0000x reference)
//
#include <hip/hip_runtime.h>
#include <math.h>

#define NN     16384
#define EE     600000
#define HIDN   128
#define NFT    32
#define NGAUSS 50
#define NLAY   6
#define TABN   8192
#define CUTF   10.0f

__device__ __forceinline__ float ssp(float x) {
    // softplus(x) - log(2), numerically stable
    return fmaxf(x, 0.0f) + log1pf(__expf(-fabsf(x))) - 0.69314718055994531f;
}

// ---------------------------------------------------------------- find ne ---
// mask = [1]*ne + [0]*(E-ne), monotone. Binary search first 0.
__global__ void find_ne(const float* __restrict__ mask, int* __restrict__ ne) {
    int lo = 0, hi = EE;
    while (lo < hi) {
        int mid = (lo + hi) >> 1;
        if (mask[mid] > 0.5f) lo = mid + 1; else hi = mid;
    }
    *ne = lo;
}

// ---------------------------------------------------------------- row_ptr ---
// dst sorted ascending over the first ne edges. rp[n] = lower_bound(dst, n).
__global__ void build_rowptr(const int* __restrict__ dst, const int* __restrict__ nep,
                             int* __restrict__ rp) {
    int n = blockIdx.x * blockDim.x + threadIdx.x;
    if (n > NN) return;
    int ne = *nep;
    if (n == NN) { rp[NN] = ne; return; }
    int lo = 0, hi = ne;
    while (lo < hi) {
        int mid = (lo + hi) >> 1;
        if (dst[mid] < n) lo = mid + 1; else hi = mid;
    }
    rp[n] = lo;
}

// ------------------------------------------------------------- edge geom ----
__global__ void edge_geom(const int* __restrict__ ei, const float* __restrict__ pos,
                          const float* __restrict__ mask,
                          float* __restrict__ de, float* __restrict__ ce) {
    int e = blockIdx.x * blockDim.x + threadIdx.x;
    if (e >= EE) return;
    int s = ei[e], t = ei[EE + e];
    float dx = pos[s * 3 + 0] - pos[t * 3 + 0];
    float dy = pos[s * 3 + 1] - pos[t * 3 + 1];
    float dz = pos[s * 3 + 2] - pos[t * 3 + 2];
    float d = sqrtf(dx * dx + dy * dy + dz * dz);
    de[e] = d;
    ce[e] = 0.5f * (cosf(d * 0.31415926535897932f) + 1.0f) * mask[e];
}

// ----------------------------------------------------------- table build ----
// tab[l][ent][f] = ( ssp(ea(d_ent) @ w1[l] + b1[l]) @ w2[l] + b2[l] )[f]
__global__ void tab_kernel(const float* __restrict__ w1, const float* __restrict__ b1,
                           const float* __restrict__ w2, const float* __restrict__ b2,
                           float* __restrict__ tab) {
    __shared__ float ea[8][NGAUSS];
    __shared__ float t1[8][NFT];
    int t = threadIdx.x, f = t & 31, g = t >> 5;
    int id = blockIdx.x * 8 + g;           // 0 .. NLAY*TABN-1 exact
    int l = id / TABN, ent = id % TABN;
    float d = ent * (CUTF / (TABN - 1));
    const float delta = CUTF / (NGAUSS - 1);
    const float coeff = -0.5f / (delta * delta);
    for (int gg = f; gg < NGAUSS; gg += 32) {
        float diff = d - gg * delta;
        ea[g][gg] = __expf(coeff * diff * diff);
    }
    __syncthreads();
    float a = b1[l * NFT + f];
    const float* w1l = w1 + l * NGAUSS * NFT;
    #pragma unroll
    for (int gg = 0; gg < NGAUSS; ++gg)
        a = fmaf(ea[g][gg], w1l[gg * NFT + f], a);
    t1[g][f] = ssp(a);
    __syncthreads();
    float c = b2[l * NFT + f];
    const float* w2l = w2 + l * NFT * NFT;
    #pragma unroll
    for (int k = 0; k < NFT; ++k)
        c = fmaf(t1[g][k], w2l[k * NFT + f], c);
    tab[(size_t)id * NFT + f] = c;
}

// ---------------------------------------------------------------- init h ----
__global__ void init_h(const int* __restrict__ z, const float4* __restrict__ emb4,
                       float4* __restrict__ h4) {
    int tid = blockIdx.x * blockDim.x + threadIdx.x;   // N*32 threads
    int n = tid >> 5, c = tid & 31;
    h4[tid] = emb4[(size_t)z[n] * 32 + c];
}

// ------------------------------------------------------------- hw = h@l1 ----
__global__ void hw_kernel(const float* __restrict__ h, const float* __restrict__ l1,
                          float* __restrict__ hw) {
    __shared__ float l1s[HIDN * NFT];
    int t = threadIdx.x, f = t & 31, nl = t >> 5;
    for (int i = t; i < HIDN * NFT / 4; i += 256)
        ((float4*)l1s)[i] = ((const float4*)l1)[i];
    __syncthreads();
    int n = blockIdx.x * 8 + nl;
    const float4* h4 = (const float4*)(h + (size_t)n * HIDN);
    float acc = 0.0f;
    #pragma unroll
    for (int k4 = 0; k4 < 32; ++k4) {
        float4 hv = h4[k4];
        acc = fmaf(hv.x, l1s[(k4 * 4 + 0) * NFT + f], acc);
        acc = fmaf(hv.y, l1s[(k4 * 4 + 1) * NFT + f], acc);
        acc = fmaf(hv.z, l1s[(k4 * 4 + 2) * NFT + f], acc);
        acc = fmaf(hv.w, l1s[(k4 * 4 + 3) * NFT + f], acc);
    }
    hw[(size_t)n * NFT + f] = acc;
}

// -------------------------------------------------- edge aggregate (CSR) ----
// 32 lanes per dst node; lane f owns feature f. No atomics.
__global__ void edge_agg(const int* __restrict__ rp, const int* __restrict__ src,
                         const float* __restrict__ de, const float* __restrict__ ce,
                         const float* __restrict__ tabL, const float* __restrict__ hw,
                         float* __restrict__ m) {
    int t = threadIdx.x, f = t & 31, g = t >> 5;
    int n = blockIdx.x * 8 + g;
    int r0 = rp[n], r1 = rp[n + 1];
    const float TS = (TABN - 1) / CUTF;
    float acc = 0.0f;
    for (int e = r0; e < r1; ++e) {
        int s = src[e];
        float d = de[e];
        float cc = ce[e];
        float p = d * TS;
        int i0 = (int)p;
        i0 = (i0 > TABN - 2) ? (TABN - 2) : i0;
        float fr = p - (float)i0;
        float w0 = tabL[(size_t)i0 * NFT + f];
        float w1v = tabL[(size_t)i0 * NFT + NFT + f];
        float w = fmaf(fr, w1v - w0, w0);
        acc = fmaf(hw[(size_t)s * NFT + f], w * cc, acc);
    }
    m[(size_t)n * NFT + f] = acc;
}

// ------------------------------------------- node update (two fused GEMMs) --
// x = ssp(m @ l2w + l2b);  h += x @ lw + lb
// 64 nodes/block, 512 threads, 4x4 register micro-tile.
// Weights read straight from global (L1/L2-resident broadcast, identical
// across blocks); LDS holds only m (8 KB) and x (32 KB) which need
// cross-lane exchange. 40 KB LDS -> 4 blocks/CU -> 32 waves (full occupancy).
#define FMA_ROW(acc, xv, wv)              \
    acc[0] = fmaf(xv, wv.x, acc[0]);      \
    acc[1] = fmaf(xv, wv.y, acc[1]);      \
    acc[2] = fmaf(xv, wv.z, acc[2]);      \
    acc[3] = fmaf(xv, wv.w, acc[3]);

__global__ __launch_bounds__(512) void node_update(
        const float* __restrict__ mg, const float* __restrict__ l2w,
        const float* __restrict__ l2b, const float* __restrict__ lwg,
        const float* __restrict__ lb, float* __restrict__ h) {
    __shared__ float xs[64 * HIDN];         // 32 KB
    __shared__ float ms[64 * NFT];          // 8 KB

    const int t  = threadIdx.x;
    const int n0 = (t >> 5) << 2;           // 0..60
    const int f0 = (t & 31) << 2;           // 0..124
    const int nb = blockIdx.x << 6;

    for (int i = t; i < 64 * NFT / 4; i += 512)
        ((float4*)ms)[i] = ((const float4*)(mg + (size_t)nb * NFT))[i];
    __syncthreads();

    // phase A: a = m @ l2w + l2b  (K = 32)
    float a[4][4];
    {
        float4 bv = *(const float4*)(l2b + f0);
        #pragma unroll
        for (int i = 0; i < 4; ++i) {
            a[i][0] = bv.x; a[i][1] = bv.y; a[i][2] = bv.z; a[i][3] = bv.w;
        }
    }
    #pragma unroll 4
    for (int k = 0; k < NFT; k += 4) {
        float4 w0 = *(const float4*)(l2w + (size_t)(k + 0) * HIDN + f0);
        float4 w1 = *(const float4*)(l2w + (size_t)(k + 1) * HIDN + f0);
        float4 w2 = *(const float4*)(l2w + (size_t)(k + 2) * HIDN + f0);
        float4 w3 = *(const float4*)(l2w + (size_t)(k + 3) * HIDN + f0);
        #pragma unroll
        for (int i = 0; i < 4; ++i) {
            float4 mv = *(const float4*)(ms + (n0 + i) * NFT + k);
            FMA_ROW(a[i], mv.x, w0);
            FMA_ROW(a[i], mv.y, w1);
            FMA_ROW(a[i], mv.z, w2);
            FMA_ROW(a[i], mv.w, w3);
        }
    }
    #pragma unroll
    for (int i = 0; i < 4; ++i) {
        float4 xv;
        xv.x = ssp(a[i][0]); xv.y = ssp(a[i][1]);
        xv.z = ssp(a[i][2]); xv.w = ssp(a[i][3]);
        *(float4*)(xs + (n0 + i) * HIDN + f0) = xv;
    }
    __syncthreads();

    // phase B: b = x @ lw + lb  (K = 128); h += b
    float b[4][4];
    {
        float4 bv = *(const float4*)(lb + f0);
        #pragma unroll
        for (int i = 0; i < 4; ++i) {
            b[i][0] = bv.x; b[i][1] = bv.y; b[i][2] = bv.z; b[i][3] = bv.w;
        }
    }
    #pragma unroll 4
    for (int j = 0; j < HIDN; j += 4) {
        float4 w0 = *(const float4*)(lwg + (size_t)(j + 0) * HIDN + f0);
        float4 w1 = *(const float4*)(lwg + (size_t)(j + 1) * HIDN + f0);
        float4 w2 = *(const float4*)(lwg + (size_t)(j + 2) * HIDN + f0);
        float4 w3 = *(const float4*)(lwg + (size_t)(j + 3) * HIDN + f0);
        #pragma unroll
        for (int i = 0; i < 4; ++i) {
            float4 xv = *(const float4*)(xs + (n0 + i) * HIDN + j);
            FMA_ROW(b[i], xv.x, w0);
            FMA_ROW(b[i], xv.y, w1);
            FMA_ROW(b[i], xv.z, w2);
            FMA_ROW(b[i], xv.w, w3);
        }
    }
    #pragma unroll
    for (int i = 0; i < 4; ++i) {
        float* hp = h + (size_t)(nb + n0 + i) * HIDN + f0;
        float4 hv = *(float4*)hp;
        hv.x += b[i][0]; hv.y += b[i][1]; hv.z += b[i][2]; hv.w += b[i][3];
        *(float4*)hp = hv;
    }
}

// ---------------------------------------------------------------------------
extern "C" void kernel_launch(void* const* d_in, const int* in_sizes, int n_in,
                              void* d_out, int out_size, void* d_ws, size_t ws_size,
                              hipStream_t stream) {
    const int*   z    = (const int*)d_in[0];
    const float* pos  = (const float*)d_in[1];
    const int*   ei   = (const int*)d_in[2];    // [2][E]
    const float* mask = (const float*)d_in[3];
    const float* emb  = (const float*)d_in[4];
    const float* w1   = (const float*)d_in[5];  // [6][50][32]
    const float* b1   = (const float*)d_in[6];  // [6][32]
    const float* w2   = (const float*)d_in[7];  // [6][32][32]
    const float* b2   = (const float*)d_in[8];  // [6][32]
    const float* l1w  = (const float*)d_in[9];  // [6][128][32]
    const float* l2w  = (const float*)d_in[10]; // [6][32][128]
    const float* l2b  = (const float*)d_in[11]; // [6][128]
    const float* lww  = (const float*)d_in[12]; // [6][128][128]
    const float* lbb  = (const float*)d_in[13]; // [6][128]
    float* h = (float*)d_out;

    char* base = (char*)d_ws;
    size_t o = 0;
    auto alloc = [&](size_t bytes) -> void* {
        void* p = base + o;
        o += (bytes + 255) & ~(size_t)255;
        return p;
    };
    int*   d_ne  = (int*)alloc(sizeof(int));
    int*   d_rp  = (int*)alloc((NN + 1) * sizeof(int));
    float* d_de  = (float*)alloc((size_t)EE * sizeof(float));
    float* d_ce  = (float*)alloc((size_t)EE * sizeof(float));
    float* d_tab = (float*)alloc((size_t)NLAY * TABN * NFT * sizeof(float));
    float* d_hw  = (float*)alloc((size_t)NN * NFT * sizeof(float));
    float* d_m   = (float*)alloc((size_t)NN * NFT * sizeof(float));
    (void)ws_size; (void)in_sizes; (void)n_in; (void)out_size;

    find_ne<<<1, 1, 0, stream>>>(mask, d_ne);
    build_rowptr<<<(NN + 1 + 255) / 256, 256, 0, stream>>>(ei + EE, d_ne, d_rp);
    edge_geom<<<(EE + 255) / 256, 256, 0, stream>>>(ei, pos, mask, d_de, d_ce);
    tab_kernel<<<NLAY * TABN / 8, 256, 0, stream>>>(w1, b1, w2, b2, d_tab);
    init_h<<<NN * 32 / 256, 256, 0, stream>>>(z, (const float4*)emb, (float4*)h);

    for (int l = 0; l < NLAY; ++l) {
        hw_kernel<<<NN / 8, 256, 0, stream>>>(h, l1w + (size_t)l * HIDN * NFT, d_hw);
        edge_agg<<<NN / 8, 256, 0, stream>>>(d_rp, ei, d_de, d_ce,
                                             d_tab + (size_t)l * TABN * NFT, d_hw, d_m);
        node_update<<<NN / 64, 512, 0, stream>>>(
            d_m, l2w + (size_t)l * NFT * HIDN, l2b + (size_t)l * HIDN,
            lww + (size_t)l * HIDN * HIDN, lbb + (size_t)l * HIDN, h);
    }
}

// Round 3
// 368.248 us; speedup vs baseline: 1.2634x; 1.2634x over previous
//
#include <hip/hip_runtime.h>
#include <math.h>

#define NN     16384
#define EE     600000
#define HIDN   128
#define NFT    32
#define NGAUSS 50
#define NLAY   6
#define TABN   8192
#define CUTF   10.0f

typedef float f32x4  __attribute__((ext_vector_type(4)));
typedef short bf16x8 __attribute__((ext_vector_type(8)));

__device__ __forceinline__ float ssp(float x) {
    // softplus(x) - log(2), numerically stable
    return fmaxf(x, 0.0f) + log1pf(__expf(-fabsf(x))) - 0.69314718055994531f;
}

__device__ __forceinline__ short f2bf(float x) {
    // f32 -> bf16 round-to-nearest-even
    union { float f; unsigned u; } v; v.f = x;
    unsigned r = v.u + 0x7fffu + ((v.u >> 16) & 1u);
    return (short)(r >> 16);
}

// ---------------------------------------------------------------- row_ptr ---
// Real edges (mask>0.5) are a prefix with dst ascending; padding after.
// key(e) = real ? dst[e] : INT_MAX is monotone -> per-thread lower_bound.
// rp[NN] = count of real edges.
__global__ void build_rowptr(const int* __restrict__ dst, const float* __restrict__ mask,
                             int* __restrict__ rp) {
    int n = blockIdx.x * blockDim.x + threadIdx.x;
    if (n > NN) return;
    int lo = 0, hi = EE;
    while (lo < hi) {
        int mid = (lo + hi) >> 1;
        int key = (mask[mid] > 0.5f) ? dst[mid] : 0x7fffffff;
        if (key < n) lo = mid + 1; else hi = mid;
    }
    rp[n] = lo;
}

// ------------------------------------------------------------- edge geom ----
__global__ void edge_geom(const int* __restrict__ ei, const float* __restrict__ pos,
                          const float* __restrict__ mask,
                          float* __restrict__ de, float* __restrict__ ce) {
    int e = blockIdx.x * blockDim.x + threadIdx.x;
    if (e >= EE) return;
    int s = ei[e], t = ei[EE + e];
    float dx = pos[s * 3 + 0] - pos[t * 3 + 0];
    float dy = pos[s * 3 + 1] - pos[t * 3 + 1];
    float dz = pos[s * 3 + 2] - pos[t * 3 + 2];
    float d = sqrtf(dx * dx + dy * dy + dz * dz);
    de[e] = d;
    ce[e] = 0.5f * (cosf(d * 0.31415926535897932f) + 1.0f) * mask[e];
}

// ----------------------------------------------------------- table build ----
__global__ void tab_kernel(const float* __restrict__ w1, const float* __restrict__ b1,
                           const float* __restrict__ w2, const float* __restrict__ b2,
                           float* __restrict__ tab) {
    __shared__ float ea[8][NGAUSS];
    __shared__ float t1[8][NFT];
    int t = threadIdx.x, f = t & 31, g = t >> 5;
    int id = blockIdx.x * 8 + g;           // 0 .. NLAY*TABN-1 exact
    int l = id / TABN, ent = id % TABN;
    float d = ent * (CUTF / (TABN - 1));
    const float delta = CUTF / (NGAUSS - 1);
    const float coeff = -0.5f / (delta * delta);
    for (int gg = f; gg < NGAUSS; gg += 32) {
        float diff = d - gg * delta;
        ea[g][gg] = __expf(coeff * diff * diff);
    }
    __syncthreads();
    float a = b1[l * NFT + f];
    const float* w1l = w1 + l * NGAUSS * NFT;
    #pragma unroll
    for (int gg = 0; gg < NGAUSS; ++gg)
        a = fmaf(ea[g][gg], w1l[gg * NFT + f], a);
    t1[g][f] = ssp(a);
    __syncthreads();
    float c = b2[l * NFT + f];
    const float* w2l = w2 + l * NFT * NFT;
    #pragma unroll
    for (int k = 0; k < NFT; ++k)
        c = fmaf(t1[g][k], w2l[k * NFT + f], c);
    tab[(size_t)id * NFT + f] = c;
}

// ---------------------------------------------------------------- init h ----
__global__ void init_h(const int* __restrict__ z, const float4* __restrict__ emb4,
                       float4* __restrict__ h4) {
    int tid = blockIdx.x * blockDim.x + threadIdx.x;   // N*32 threads
    int n = tid >> 5, c = tid & 31;
    h4[tid] = emb4[(size_t)z[n] * 32 + c];
}

// --------------------------------------------------------- weight prep ------
// Transpose + bf16-convert all layer weights once:
//  l2wT[l][f<128][k<32]  = l2w[l][k][f]
//  lwT [l][f<128][k<128] = lw [l][k][f]
//  l1T [l][f<32 ][k<128] = l1 [l][k][f]
__global__ void prep_weights(const float* __restrict__ l2w, const float* __restrict__ lww,
                             const float* __restrict__ l1w,
                             short* __restrict__ l2wT, short* __restrict__ lwT,
                             short* __restrict__ l1T) {
    const int per = 4096 + 16384 + 4096;   // 24576 per layer
    int id = blockIdx.x * blockDim.x + threadIdx.x;
    if (id >= NLAY * per) return;
    int l = id / per, r = id % per;
    if (r < 4096) {
        int f = r >> 5, k = r & 31;
        l2wT[l * 4096 + f * 32 + k] = f2bf(l2w[l * 4096 + k * 128 + f]);
    } else if (r < 4096 + 16384) {
        int q = r - 4096; int f = q >> 7, k = q & 127;
        lwT[l * 16384 + f * 128 + k] = f2bf(lww[l * 16384 + k * 128 + f]);
    } else {
        int q = r - 20480; int f = q >> 7, k = q & 127;   // f<32, k<128
        l1T[l * 4096 + f * 128 + k] = f2bf(l1w[l * 4096 + k * 32 + f]);
    }
}

// ------------------------------------------------- hw = h@l1 (layer 0) ------
__global__ void hw_kernel(const float* __restrict__ h, const float* __restrict__ l1,
                          float* __restrict__ hw) {
    __shared__ float l1s[HIDN * NFT];
    int t = threadIdx.x, f = t & 31, nl = t >> 5;
    for (int i = t; i < HIDN * NFT / 4; i += 256)
        ((float4*)l1s)[i] = ((const float4*)l1)[i];
    __syncthreads();
    int n = blockIdx.x * 8 + nl;
    const float4* h4 = (const float4*)(h + (size_t)n * HIDN);
    float acc = 0.0f;
    #pragma unroll
    for (int k4 = 0; k4 < 32; ++k4) {
        float4 hv = h4[k4];
        acc = fmaf(hv.x, l1s[(k4 * 4 + 0) * NFT + f], acc);
        acc = fmaf(hv.y, l1s[(k4 * 4 + 1) * NFT + f], acc);
        acc = fmaf(hv.z, l1s[(k4 * 4 + 2) * NFT + f], acc);
        acc = fmaf(hv.w, l1s[(k4 * 4 + 3) * NFT + f], acc);
    }
    hw[(size_t)n * NFT + f] = acc;
}

// -------------------------------------------------- edge aggregate (CSR) ----
__global__ void edge_agg(const int* __restrict__ rp, const int* __restrict__ src,
                         const float* __restrict__ de, const float* __restrict__ ce,
                         const float* __restrict__ tabL, const float* __restrict__ hw,
                         float* __restrict__ m) {
    int t = threadIdx.x, f = t & 31, g = t >> 5;
    int n = blockIdx.x * 8 + g;
    int r0 = rp[n], r1 = rp[n + 1];
    const float TS = (TABN - 1) / CUTF;
    float acc = 0.0f;
    for (int e = r0; e < r1; ++e) {
        int s = src[e];
        float d = de[e];
        float cc = ce[e];
        float p = d * TS;
        int i0 = (int)p;
        i0 = (i0 > TABN - 2) ? (TABN - 2) : i0;
        float fr = p - (float)i0;
        float w0 = tabL[(size_t)i0 * NFT + f];
        float w1v = tabL[(size_t)i0 * NFT + NFT + f];
        float w = fmaf(fr, w1v - w0, w0);
        acc = fmaf(hw[(size_t)s * NFT + f], w * cc, acc);
    }
    m[(size_t)n * NFT + f] = acc;
}

// --------------------------------- node update, MFMA (+ fused next-layer hw)
// x = ssp(m@l2w + l2b); h += x@lw + lb; hw_next = h_new @ l1[l+1]
// 256 threads = 4 waves; wave w owns node rows [nb+16w, nb+16w+16).
// mfma_f32_16x16x32_bf16 layouts (m89/m91-verified):
//   A: lane(16g+r) holds A[r][8g..8g+7];  B: lane(16g+c) holds B[8g..8g+7][c]
//   C/D: col = lane&15, row = 4*(lane>>4) + reg
// xs LDS tile is intra-wave only (transpose between D-layout and A-layout)
// -> no __syncthreads needed. XOR-swizzle (G4): 16B-granule ^= (row&7).
__global__ __launch_bounds__(256) void node_update_mfma(
        const float* __restrict__ mg, const short* __restrict__ l2wT,
        const float* __restrict__ l2b, const short* __restrict__ lwT,
        const float* __restrict__ lb, float* __restrict__ h,
        const short* __restrict__ l1Tn, float* __restrict__ hwn) {
    __shared__ short xs[64 * 128];          // 16 KB, bf16, swizzled
    const int t  = threadIdx.x;
    const int w  = t >> 6;                  // wave 0..3
    const int l  = t & 63;
    const int lr = l & 15;                  // row/col within 16-tile
    const int lg = l >> 4;                  // k-group 0..3
    const int nb = blockIdx.x << 6;
    const int nodew = nb + w * 16;          // first node of this wave

    // ---- A-frag of m: m[nodew+lr][lg*8 .. lg*8+7], f32 global -> bf16
    bf16x8 ma;
    {
        const float* mrow = mg + (size_t)(nodew + lr) * NFT + lg * 8;
        f32x4 m0 = *(const f32x4*)(mrow);
        f32x4 m1 = *(const f32x4*)(mrow + 4);
        ma[0] = f2bf(m0.x); ma[1] = f2bf(m0.y); ma[2] = f2bf(m0.z); ma[3] = f2bf(m0.w);
        ma[4] = f2bf(m1.x); ma[5] = f2bf(m1.y); ma[6] = f2bf(m1.z); ma[7] = f2bf(m1.w);
    }

    // ---- phase A: x = ssp(m @ l2w + l2b), K=32 (one MFMA per f-tile)
    #pragma unroll
    for (int ft = 0; ft < 8; ++ft) {
        bf16x8 bw = *(const bf16x8*)(l2wT + (ft * 16 + lr) * 32 + lg * 8);
        f32x4 c = {0.f, 0.f, 0.f, 0.f};
        c = __builtin_amdgcn_mfma_f32_16x16x32_bf16(ma, bw, c, 0, 0, 0);
        float bias = l2b[ft * 16 + lr];
        #pragma unroll
        for (int i = 0; i < 4; ++i) {
            int row = w * 16 + lg * 4 + i;          // node row within 64
            int col = ft * 16 + lr;                 // feature 0..127
            int pos = ((col >> 3) ^ (row & 7)) * 8 + (col & 7);
            xs[row * 128 + pos] = f2bf(ssp(c[i] + bias));
        }
    }
    // intra-wave LDS write->read: compiler inserts lgkmcnt; no barrier needed

    // ---- phase B A-frags: x[nodew+lr][ks*32 + lg*8 ..], swizzled read
    bf16x8 xa[4];
    #pragma unroll
    for (int ks = 0; ks < 4; ++ks)
        xa[ks] = *(const bf16x8*)(xs + (w * 16 + lr) * 128 + ((ks * 4 + lg) ^ (lr & 7)) * 8);

    // ---- phase B: h += x @ lw + lb  (K=128); stash h_new bf16 back in xs
    #pragma unroll
    for (int ft = 0; ft < 8; ++ft) {
        f32x4 c = {0.f, 0.f, 0.f, 0.f};
        #pragma unroll
        for (int ks = 0; ks < 4; ++ks) {
            bf16x8 bw = *(const bf16x8*)(lwT + (ft * 16 + lr) * 128 + ks * 32 + lg * 8);
            c = __builtin_amdgcn_mfma_f32_16x16x32_bf16(xa[ks], bw, c, 0, 0, 0);
        }
        float bias = lb[ft * 16 + lr];
        #pragma unroll
        for (int i = 0; i < 4; ++i) {
            int node = nodew + lg * 4 + i;
            float* hp = h + (size_t)node * HIDN + ft * 16 + lr;
            float hv = *hp + c[i] + bias;
            *hp = hv;
            int row = w * 16 + lg * 4 + i;
            int col = ft * 16 + lr;
            int pos = ((col >> 3) ^ (row & 7)) * 8 + (col & 7);
            xs[row * 128 + pos] = f2bf(hv);
        }
    }

    // ---- fused next-layer hw = h_new @ l1[l+1]  (N=32)
    if (l1Tn != nullptr) {
        bf16x8 ha[4];
        #pragma unroll
        for (int ks = 0; ks < 4; ++ks)
            ha[ks] = *(const bf16x8*)(xs + (w * 16 + lr) * 128 + ((ks * 4 + lg) ^ (lr & 7)) * 8);
        #pragma unroll
        for (int ft = 0; ft < 2; ++ft) {
            f32x4 c = {0.f, 0.f, 0.f, 0.f};
            #pragma unroll
            for (int ks = 0; ks < 4; ++ks) {
                bf16x8 bw = *(const bf16x8*)(l1Tn + (ft * 16 + lr) * 128 + ks * 32 + lg * 8);
                c = __builtin_amdgcn_mfma_f32_16x16x32_bf16(ha[ks], bw, c, 0, 0, 0);
            }
            #pragma unroll
            for (int i = 0; i < 4; ++i) {
                int node = nodew + lg * 4 + i;
                hwn[(size_t)node * NFT + ft * 16 + lr] = c[i];
            }
        }
    }
}

// ---------------------------------------------------------------------------
extern "C" void kernel_launch(void* const* d_in, const int* in_sizes, int n_in,
                              void* d_out, int out_size, void* d_ws, size_t ws_size,
                              hipStream_t stream) {
    const int*   z    = (const int*)d_in[0];
    const float* pos  = (const float*)d_in[1];
    const int*   ei   = (const int*)d_in[2];    // [2][E]
    const float* mask = (const float*)d_in[3];
    const float* emb  = (const float*)d_in[4];
    const float* w1   = (const float*)d_in[5];  // [6][50][32]
    const float* b1   = (const float*)d_in[6];  // [6][32]
    const float* w2   = (const float*)d_in[7];  // [6][32][32]
    const float* b2   = (const float*)d_in[8];  // [6][32]
    const float* l1w  = (const float*)d_in[9];  // [6][128][32]
    const float* l2w  = (const float*)d_in[10]; // [6][32][128]
    const float* l2b  = (const float*)d_in[11]; // [6][128]
    const float* lww  = (const float*)d_in[12]; // [6][128][128]
    const float* lbb  = (const float*)d_in[13]; // [6][128]
    float* h = (float*)d_out;

    char* base = (char*)d_ws;
    size_t o = 0;
    auto alloc = [&](size_t bytes) -> void* {
        void* p = base + o;
        o += (bytes + 255) & ~(size_t)255;
        return p;
    };
    int*   d_rp   = (int*)alloc((NN + 1) * sizeof(int));
    float* d_de   = (float*)alloc((size_t)EE * sizeof(float));
    float* d_ce   = (float*)alloc((size_t)EE * sizeof(float));
    float* d_tab  = (float*)alloc((size_t)NLAY * TABN * NFT * sizeof(float));
    float* d_hw   = (float*)alloc((size_t)NN * NFT * sizeof(float));
    float* d_m    = (float*)alloc((size_t)NN * NFT * sizeof(float));
    short* d_l2wT = (short*)alloc((size_t)NLAY * 4096 * sizeof(short));
    short* d_lwT  = (short*)alloc((size_t)NLAY * 16384 * sizeof(short));
    short* d_l1T  = (short*)alloc((size_t)NLAY * 4096 * sizeof(short));
    (void)ws_size; (void)in_sizes; (void)n_in; (void)out_size;

    prep_weights<<<(NLAY * 24576 + 255) / 256, 256, 0, stream>>>(
        l2w, lww, l1w, d_l2wT, d_lwT, d_l1T);
    build_rowptr<<<(NN + 1 + 255) / 256, 256, 0, stream>>>(ei + EE, mask, d_rp);
    edge_geom<<<(EE + 255) / 256, 256, 0, stream>>>(ei, pos, mask, d_de, d_ce);
    tab_kernel<<<NLAY * TABN / 8, 256, 0, stream>>>(w1, b1, w2, b2, d_tab);
    init_h<<<NN * 32 / 256, 256, 0, stream>>>(z, (const float4*)emb, (float4*)h);
    hw_kernel<<<NN / 8, 256, 0, stream>>>(h, l1w, d_hw);   // layer-0 hw (f32)

    for (int l = 0; l < NLAY; ++l) {
        edge_agg<<<NN / 8, 256, 0, stream>>>(d_rp, ei, d_de, d_ce,
                                             d_tab + (size_t)l * TABN * NFT, d_hw, d_m);
        const short* l1Tn = (l + 1 < NLAY) ? (d_l1T + (size_t)(l + 1) * 4096) : nullptr;
        node_update_mfma<<<NN / 64, 256, 0, stream>>>(
            d_m, d_l2wT + (size_t)l * 4096, l2b + (size_t)l * HIDN,
            d_lwT + (size_t)l * 16384, lbb + (size_t)l * HIDN, h, l1Tn, d_hw);
    }
}

// Round 4
// 300.424 us; speedup vs baseline: 1.5486x; 1.2258x over previous
//
#include <hip/hip_runtime.h>
#include <math.h>

#define NN     16384
#define EE     600000
#define HIDN   128
#define NFT    32
#define NGAUSS 50
#define NLAY   6
#define TABN   8192
#define CUTF   10.0f

typedef float f32x4  __attribute__((ext_vector_type(4)));
typedef short bf16x8 __attribute__((ext_vector_type(8)));

__device__ __forceinline__ float ssp(float x) {
    // softplus(x) - log(2), numerically stable
    return fmaxf(x, 0.0f) + log1pf(__expf(-fabsf(x))) - 0.69314718055994531f;
}

__device__ __forceinline__ short f2bf(float x) {
    // f32 -> bf16 round-to-nearest-even
    union { float f; unsigned u; } v; v.f = x;
    unsigned r = v.u + 0x7fffu + ((v.u >> 16) & 1u);
    return (short)(r >> 16);
}

// ---------------------------------------------------------------- row_ptr ---
// Real edges (mask>0.5) are a prefix with dst ascending; padding after.
// key(e) = real ? dst[e] : INT_MAX is monotone -> per-thread lower_bound.
__global__ void build_rowptr(const int* __restrict__ dst, const float* __restrict__ mask,
                             int* __restrict__ rp) {
    int n = blockIdx.x * blockDim.x + threadIdx.x;
    if (n > NN) return;
    int lo = 0, hi = EE;
    while (lo < hi) {
        int mid = (lo + hi) >> 1;
        int key = (mask[mid] > 0.5f) ? dst[mid] : 0x7fffffff;
        if (key < n) lo = mid + 1; else hi = mid;
    }
    rp[n] = lo;
}

// ------------------------------------------------------------- edge geom ----
__global__ void edge_geom(const int* __restrict__ ei, const float* __restrict__ pos,
                          const float* __restrict__ mask,
                          float* __restrict__ de, float* __restrict__ ce) {
    int e = blockIdx.x * blockDim.x + threadIdx.x;
    if (e >= EE) return;
    int s = ei[e], t = ei[EE + e];
    float dx = pos[s * 3 + 0] - pos[t * 3 + 0];
    float dy = pos[s * 3 + 1] - pos[t * 3 + 1];
    float dz = pos[s * 3 + 2] - pos[t * 3 + 2];
    float d = sqrtf(dx * dx + dy * dy + dz * dz);
    de[e] = d;
    ce[e] = 0.5f * (cosf(d * 0.31415926535897932f) + 1.0f) * mask[e];
}

// ----------------------------------------------------------- table build ----
__global__ void tab_kernel(const float* __restrict__ w1, const float* __restrict__ b1,
                           const float* __restrict__ w2, const float* __restrict__ b2,
                           float* __restrict__ tab) {
    __shared__ float ea[8][NGAUSS];
    __shared__ float t1[8][NFT];
    int t = threadIdx.x, f = t & 31, g = t >> 5;
    int id = blockIdx.x * 8 + g;           // 0 .. NLAY*TABN-1 exact
    int l = id / TABN, ent = id % TABN;
    float d = ent * (CUTF / (TABN - 1));
    const float delta = CUTF / (NGAUSS - 1);
    const float coeff = -0.5f / (delta * delta);
    for (int gg = f; gg < NGAUSS; gg += 32) {
        float diff = d - gg * delta;
        ea[g][gg] = __expf(coeff * diff * diff);
    }
    __syncthreads();
    float a = b1[l * NFT + f];
    const float* w1l = w1 + l * NGAUSS * NFT;
    #pragma unroll
    for (int gg = 0; gg < NGAUSS; ++gg)
        a = fmaf(ea[g][gg], w1l[gg * NFT + f], a);
    t1[g][f] = ssp(a);
    __syncthreads();
    float c = b2[l * NFT + f];
    const float* w2l = w2 + l * NFT * NFT;
    #pragma unroll
    for (int k = 0; k < NFT; ++k)
        c = fmaf(t1[g][k], w2l[k * NFT + f], c);
    tab[(size_t)id * NFT + f] = c;
}

// ---------------------------------------------------------------- init h ----
__global__ void init_h(const int* __restrict__ z, const float4* __restrict__ emb4,
                       float4* __restrict__ h4) {
    int tid = blockIdx.x * blockDim.x + threadIdx.x;   // N*32 threads
    int n = tid >> 5, c = tid & 31;
    h4[tid] = emb4[(size_t)z[n] * 32 + c];
}

// --------------------------------------------------------- weight prep ------
//  l2wT[l][f<128][k<32]  = l2w[l][k][f]
//  lwT [l][f<128][k<128] = lw [l][k][f]
//  l1T [l][f<32 ][k<128] = l1 [l][k][f]
__global__ void prep_weights(const float* __restrict__ l2w, const float* __restrict__ lww,
                             const float* __restrict__ l1w,
                             short* __restrict__ l2wT, short* __restrict__ lwT,
                             short* __restrict__ l1T) {
    const int per = 4096 + 16384 + 4096;   // 24576 per layer
    int id = blockIdx.x * blockDim.x + threadIdx.x;
    if (id >= NLAY * per) return;
    int l = id / per, r = id % per;
    if (r < 4096) {
        int f = r >> 5, k = r & 31;
        l2wT[l * 4096 + f * 32 + k] = f2bf(l2w[l * 4096 + k * 128 + f]);
    } else if (r < 4096 + 16384) {
        int q = r - 4096; int f = q >> 7, k = q & 127;
        lwT[l * 16384 + f * 128 + k] = f2bf(lww[l * 16384 + k * 128 + f]);
    } else {
        int q = r - 20480; int f = q >> 7, k = q & 127;   // f<32, k<128
        l1T[l * 4096 + f * 128 + k] = f2bf(l1w[l * 4096 + k * 32 + f]);
    }
}

// ------------------------------------------------- hw = h@l1 (layer 0) ------
__global__ void hw_kernel(const float* __restrict__ h, const float* __restrict__ l1,
                          float* __restrict__ hw) {
    __shared__ float l1s[HIDN * NFT];
    int t = threadIdx.x, f = t & 31, nl = t >> 5;
    for (int i = t; i < HIDN * NFT / 4; i += 256)
        ((float4*)l1s)[i] = ((const float4*)l1)[i];
    __syncthreads();
    int n = blockIdx.x * 8 + nl;
    const float4* h4 = (const float4*)(h + (size_t)n * HIDN);
    float acc = 0.0f;
    #pragma unroll
    for (int k4 = 0; k4 < 32; ++k4) {
        float4 hv = h4[k4];
        acc = fmaf(hv.x, l1s[(k4 * 4 + 0) * NFT + f], acc);
        acc = fmaf(hv.y, l1s[(k4 * 4 + 1) * NFT + f], acc);
        acc = fmaf(hv.z, l1s[(k4 * 4 + 2) * NFT + f], acc);
        acc = fmaf(hv.w, l1s[(k4 * 4 + 3) * NFT + f], acc);
    }
    hw[(size_t)n * NFT + f] = acc;
}

// -------------------------------------------------- edge aggregate (CSR) ----
__global__ void edge_agg(const int* __restrict__ rp, const int* __restrict__ src,
                         const float* __restrict__ de, const float* __restrict__ ce,
                         const float* __restrict__ tabL, const float* __restrict__ hw,
                         float* __restrict__ m) {
    int t = threadIdx.x, f = t & 31, g = t >> 5;
    int n = blockIdx.x * 8 + g;
    int r0 = rp[n], r1 = rp[n + 1];
    const float TS = (TABN - 1) / CUTF;
    float acc = 0.0f;
    for (int e = r0; e < r1; ++e) {
        int s = src[e];
        float d = de[e];
        float cc = ce[e];
        float p = d * TS;
        int i0 = (int)p;
        i0 = (i0 > TABN - 2) ? (TABN - 2) : i0;
        float fr = p - (float)i0;
        float w0 = tabL[(size_t)i0 * NFT + f];
        float w1v = tabL[(size_t)i0 * NFT + NFT + f];
        float w = fmaf(fr, w1v - w0, w0);
        acc = fmaf(hw[(size_t)s * NFT + f], w * cc, acc);
    }
    m[(size_t)n * NFT + f] = acc;
}

// --------------------------------- node update, MFMA (+ fused next-layer hw)
// x = ssp(m@l2w + l2b); h += x@lw + lb; hw_next = h_new @ l1[l+1]
// 512 threads = 8 waves; block owns 32 nodes. Wave (ng = w&1, fh = w>>1):
// node group ng (16 rows), f-tile pair {2fh, 2fh+1}. Work split across waves
// for TLP: grid = 512 blocks -> 16 waves/CU (was 1 wave/SIMD before).
// mfma_f32_16x16x32_bf16 layouts (m89/m91-verified):
//   A: lane(16g+r) holds A[r][8g..8g+7];  B: lane(16g+c) holds B[8g..8g+7][c]
//   C/D: col = lane&15, row = 4*(lane>>4) + reg
// xs/hs tiles XOR-swizzled: 16B-granule ^= (row&7)  (G4).
__global__ __launch_bounds__(512) void node_update_mfma(
        const float* __restrict__ mg, const short* __restrict__ l2wT,
        const float* __restrict__ l2b, const short* __restrict__ lwT,
        const float* __restrict__ lb, float* __restrict__ h,
        const short* __restrict__ l1Tn, float* __restrict__ hwn) {
    __shared__ short xs[32 * 128];          // 8 KB bf16, swizzled
    __shared__ short hs[32 * 128];          // 8 KB bf16, swizzled
    const int t  = threadIdx.x;
    const int w  = t >> 6;                  // wave 0..7
    const int l  = t & 63;
    const int lr = l & 15;                  // row/col within 16-tile
    const int lg = l >> 4;                  // k-group 0..3
    const int ng = w & 1;                   // node group (16 nodes each)
    const int fh = w >> 1;                  // f-tile pair 0..3
    const int nb = blockIdx.x << 5;         // 32 nodes per block
    const int nodew = nb + ng * 16;
    const int rbase = ng * 16;

    // ---- A-frag of m: m[nodew+lr][lg*8 .. +7], f32 global -> bf16
    bf16x8 ma;
    {
        const float* mrow = mg + (size_t)(nodew + lr) * NFT + lg * 8;
        f32x4 m0 = *(const f32x4*)(mrow);
        f32x4 m1 = *(const f32x4*)(mrow + 4);
        ma[0] = f2bf(m0.x); ma[1] = f2bf(m0.y); ma[2] = f2bf(m0.z); ma[3] = f2bf(m0.w);
        ma[4] = f2bf(m1.x); ma[5] = f2bf(m1.y); ma[6] = f2bf(m1.z); ma[7] = f2bf(m1.w);
    }

    // ---- phase A: x = ssp(m @ l2w + l2b), 2 f-tiles per wave
    #pragma unroll
    for (int fi = 0; fi < 2; ++fi) {
        int ft = fh * 2 + fi;
        bf16x8 bw = *(const bf16x8*)(l2wT + (ft * 16 + lr) * 32 + lg * 8);
        f32x4 c = {0.f, 0.f, 0.f, 0.f};
        c = __builtin_amdgcn_mfma_f32_16x16x32_bf16(ma, bw, c, 0, 0, 0);
        float bias = l2b[ft * 16 + lr];
        #pragma unroll
        for (int i = 0; i < 4; ++i) {
            int row = rbase + lg * 4 + i;
            int col = ft * 16 + lr;
            int pos = ((col >> 3) ^ (row & 7)) * 8 + (col & 7);
            xs[row * 128 + pos] = f2bf(ssp(c[i] + bias));
        }
    }
    __syncthreads();

    // ---- phase B A-frags: x[rbase+lr][ks*32 + lg*8 ..], swizzled read
    bf16x8 xa[4];
    #pragma unroll
    for (int ks = 0; ks < 4; ++ks)
        xa[ks] = *(const bf16x8*)(xs + (rbase + lr) * 128 + ((ks * 4 + lg) ^ (lr & 7)) * 8);

    // ---- phase B: h += x @ lw + lb (K=128), 2 f-tiles; h_new bf16 -> hs
    #pragma unroll
    for (int fi = 0; fi < 2; ++fi) {
        int ft = fh * 2 + fi;
        f32x4 c = {0.f, 0.f, 0.f, 0.f};
        #pragma unroll
        for (int ks = 0; ks < 4; ++ks) {
            bf16x8 bw = *(const bf16x8*)(lwT + (ft * 16 + lr) * 128 + ks * 32 + lg * 8);
            c = __builtin_amdgcn_mfma_f32_16x16x32_bf16(xa[ks], bw, c, 0, 0, 0);
        }
        float bias = lb[ft * 16 + lr];
        #pragma unroll
        for (int i = 0; i < 4; ++i) {
            int node = nodew + lg * 4 + i;
            float* hp = h + (size_t)node * HIDN + ft * 16 + lr;
            float hv = *hp + c[i] + bias;
            *hp = hv;
            int row = rbase + lg * 4 + i;
            int col = ft * 16 + lr;
            int pos = ((col >> 3) ^ (row & 7)) * 8 + (col & 7);
            hs[row * 128 + pos] = f2bf(hv);
        }
    }

    // ---- fused next-layer hw = h_new @ l1[l+1]  (N=32 -> 2 f-tiles total)
    if (l1Tn != nullptr) {
        __syncthreads();
        if (fh < 2) {
            bf16x8 ha[4];
            #pragma unroll
            for (int ks = 0; ks < 4; ++ks)
                ha[ks] = *(const bf16x8*)(hs + (rbase + lr) * 128 + ((ks * 4 + lg) ^ (lr & 7)) * 8);
            int ft = fh;
            f32x4 c = {0.f, 0.f, 0.f, 0.f};
            #pragma unroll
            for (int ks = 0; ks < 4; ++ks) {
                bf16x8 bw = *(const bf16x8*)(l1Tn + (ft * 16 + lr) * 128 + ks * 32 + lg * 8);
                c = __builtin_amdgcn_mfma_f32_16x16x32_bf16(ha[ks], bw, c, 0, 0, 0);
            }
            #pragma unroll
            for (int i = 0; i < 4; ++i) {
                int node = nodew + lg * 4 + i;
                hwn[(size_t)node * NFT + ft * 16 + lr] = c[i];
            }
        }
    }
}

// ---------------------------------------------------------------------------
extern "C" void kernel_launch(void* const* d_in, const int* in_sizes, int n_in,
                              void* d_out, int out_size, void* d_ws, size_t ws_size,
                              hipStream_t stream) {
    const int*   z    = (const int*)d_in[0];
    const float* pos  = (const float*)d_in[1];
    const int*   ei   = (const int*)d_in[2];    // [2][E]
    const float* mask = (const float*)d_in[3];
    const float* emb  = (const float*)d_in[4];
    const float* w1   = (const float*)d_in[5];  // [6][50][32]
    const float* b1   = (const float*)d_in[6];  // [6][32]
    const float* w2   = (const float*)d_in[7];  // [6][32][32]
    const float* b2   = (const float*)d_in[8];  // [6][32]
    const float* l1w  = (const float*)d_in[9];  // [6][128][32]
    const float* l2w  = (const float*)d_in[10]; // [6][32][128]
    const float* l2b  = (const float*)d_in[11]; // [6][128]
    const float* lww  = (const float*)d_in[12]; // [6][128][128]
    const float* lbb  = (const float*)d_in[13]; // [6][128]
    float* h = (float*)d_out;

    char* base = (char*)d_ws;
    size_t o = 0;
    auto alloc = [&](size_t bytes) -> void* {
        void* p = base + o;
        o += (bytes + 255) & ~(size_t)255;
        return p;
    };
    int*   d_rp   = (int*)alloc((NN + 1) * sizeof(int));
    float* d_de   = (float*)alloc((size_t)EE * sizeof(float));
    float* d_ce   = (float*)alloc((size_t)EE * sizeof(float));
    float* d_tab  = (float*)alloc((size_t)NLAY * TABN * NFT * sizeof(float));
    float* d_hw   = (float*)alloc((size_t)NN * NFT * sizeof(float));
    float* d_m    = (float*)alloc((size_t)NN * NFT * sizeof(float));
    short* d_l2wT = (short*)alloc((size_t)NLAY * 4096 * sizeof(short));
    short* d_lwT  = (short*)alloc((size_t)NLAY * 16384 * sizeof(short));
    short* d_l1T  = (short*)alloc((size_t)NLAY * 4096 * sizeof(short));
    (void)ws_size; (void)in_sizes; (void)n_in; (void)out_size;

    prep_weights<<<(NLAY * 24576 + 255) / 256, 256, 0, stream>>>(
        l2w, lww, l1w, d_l2wT, d_lwT, d_l1T);
    build_rowptr<<<(NN + 1 + 255) / 256, 256, 0, stream>>>(ei + EE, mask, d_rp);
    edge_geom<<<(EE + 255) / 256, 256, 0, stream>>>(ei, pos, mask, d_de, d_ce);
    tab_kernel<<<NLAY * TABN / 8, 256, 0, stream>>>(w1, b1, w2, b2, d_tab);
    init_h<<<NN * 32 / 256, 256, 0, stream>>>(z, (const float4*)emb, (float4*)h);
    hw_kernel<<<NN / 8, 256, 0, stream>>>(h, l1w, d_hw);   // layer-0 hw (f32)

    for (int l = 0; l < NLAY; ++l) {
        edge_agg<<<NN / 8, 256, 0, stream>>>(d_rp, ei, d_de, d_ce,
                                             d_tab + (size_t)l * TABN * NFT, d_hw, d_m);
        const short* l1Tn = (l + 1 < NLAY) ? (d_l1T + (size_t)(l + 1) * 4096) : nullptr;
        node_update_mfma<<<NN / 32, 512, 0, stream>>>(
            d_m, d_l2wT + (size_t)l * 4096, l2b + (size_t)l * HIDN,
            d_lwT + (size_t)l * 16384, lbb + (size_t)l * HIDN, h, l1Tn, d_hw);
    }
}

// Round 5
// 235.605 us; speedup vs baseline: 1.9746x; 1.2751x over previous
//
#include <hip/hip_runtime.h>
#include <math.h>

#define NN     16384
#define EE     600000
#define HIDN   128
#define NFT    32
#define NGAUSS 50
#define NLAY   6
#define TABN   8192
#define CUTF   10.0f

typedef float f32x4  __attribute__((ext_vector_type(4)));
typedef short bf16x8 __attribute__((ext_vector_type(8)));

__device__ __forceinline__ float ssp(float x) {
    // softplus(x) - log(2), numerically stable
    return fmaxf(x, 0.0f) + log1pf(__expf(-fabsf(x))) - 0.69314718055994531f;
}

__device__ __forceinline__ short f2bf(float x) {
    // f32 -> bf16 round-to-nearest-even
    union { float f; unsigned u; } v; v.f = x;
    unsigned r = v.u + 0x7fffu + ((v.u >> 16) & 1u);
    return (short)(r >> 16);
}

// ---------------------------------------------------------------- row_ptr ---
// Real edges (mask>0.5) are a prefix with dst ascending; padding after.
// key(e) = real ? dst[e] : INT_MAX is monotone -> per-thread lower_bound.
__global__ void build_rowptr(const int* __restrict__ dst, const float* __restrict__ mask,
                             int* __restrict__ rp) {
    int n = blockIdx.x * blockDim.x + threadIdx.x;
    if (n > NN) return;
    int lo = 0, hi = EE;
    while (lo < hi) {
        int mid = (lo + hi) >> 1;
        int key = (mask[mid] > 0.5f) ? dst[mid] : 0x7fffffff;
        if (key < n) lo = mid + 1; else hi = mid;
    }
    rp[n] = lo;
}

// ------------------------------------------------------------- edge geom ----
__global__ void edge_geom(const int* __restrict__ ei, const float* __restrict__ pos,
                          const float* __restrict__ mask,
                          float* __restrict__ de, float* __restrict__ ce) {
    int e = blockIdx.x * blockDim.x + threadIdx.x;
    if (e >= EE) return;
    int s = ei[e], t = ei[EE + e];
    float dx = pos[s * 3 + 0] - pos[t * 3 + 0];
    float dy = pos[s * 3 + 1] - pos[t * 3 + 1];
    float dz = pos[s * 3 + 2] - pos[t * 3 + 2];
    float d = sqrtf(dx * dx + dy * dy + dz * dz);
    de[e] = d;
    ce[e] = 0.5f * (cosf(d * 0.31415926535897932f) + 1.0f) * mask[e];
}

// ----------------------------------------------------------- table build ----
__global__ void tab_kernel(const float* __restrict__ w1, const float* __restrict__ b1,
                           const float* __restrict__ w2, const float* __restrict__ b2,
                           float* __restrict__ tab) {
    __shared__ float ea[8][NGAUSS];
    __shared__ float t1[8][NFT];
    int t = threadIdx.x, f = t & 31, g = t >> 5;
    int id = blockIdx.x * 8 + g;           // 0 .. NLAY*TABN-1 exact
    int l = id / TABN, ent = id % TABN;
    float d = ent * (CUTF / (TABN - 1));
    const float delta = CUTF / (NGAUSS - 1);
    const float coeff = -0.5f / (delta * delta);
    for (int gg = f; gg < NGAUSS; gg += 32) {
        float diff = d - gg * delta;
        ea[g][gg] = __expf(coeff * diff * diff);
    }
    __syncthreads();
    float a = b1[l * NFT + f];
    const float* w1l = w1 + l * NGAUSS * NFT;
    #pragma unroll
    for (int gg = 0; gg < NGAUSS; ++gg)
        a = fmaf(ea[g][gg], w1l[gg * NFT + f], a);
    t1[g][f] = ssp(a);
    __syncthreads();
    float c = b2[l * NFT + f];
    const float* w2l = w2 + l * NFT * NFT;
    #pragma unroll
    for (int k = 0; k < NFT; ++k)
        c = fmaf(t1[g][k], w2l[k * NFT + f], c);
    tab[(size_t)id * NFT + f] = c;
}

// ---------------------------------------------------------------- init h ----
__global__ void init_h(const int* __restrict__ z, const float4* __restrict__ emb4,
                       float4* __restrict__ h4) {
    int tid = blockIdx.x * blockDim.x + threadIdx.x;   // N*32 threads
    int n = tid >> 5, c = tid & 31;
    h4[tid] = emb4[(size_t)z[n] * 32 + c];
}

// --------------------------------------------------------- weight prep ------
//  l2wT[l][f<128][k<32]  = l2w[l][k][f]
//  lwT [l][f<128][k<128] = lw [l][k][f]
//  l1T [l][f<32 ][k<128] = l1 [l][k][f]
__global__ void prep_weights(const float* __restrict__ l2w, const float* __restrict__ lww,
                             const float* __restrict__ l1w,
                             short* __restrict__ l2wT, short* __restrict__ lwT,
                             short* __restrict__ l1T) {
    const int per = 4096 + 16384 + 4096;   // 24576 per layer
    int id = blockIdx.x * blockDim.x + threadIdx.x;
    if (id >= NLAY * per) return;
    int l = id / per, r = id % per;
    if (r < 4096) {
        int f = r >> 5, k = r & 31;
        l2wT[l * 4096 + f * 32 + k] = f2bf(l2w[l * 4096 + k * 128 + f]);
    } else if (r < 4096 + 16384) {
        int q = r - 4096; int f = q >> 7, k = q & 127;
        lwT[l * 16384 + f * 128 + k] = f2bf(lww[l * 16384 + k * 128 + f]);
    } else {
        int q = r - 20480; int f = q >> 7, k = q & 127;   // f<32, k<128
        l1T[l * 4096 + f * 128 + k] = f2bf(l1w[l * 4096 + k * 32 + f]);
    }
}

// ------------------------------------------------- hw = h@l1 (layer 0) ------
__global__ void hw_kernel(const float* __restrict__ h, const float* __restrict__ l1,
                          float* __restrict__ hw) {
    __shared__ float l1s[HIDN * NFT];
    int t = threadIdx.x, f = t & 31, nl = t >> 5;
    for (int i = t; i < HIDN * NFT / 4; i += 256)
        ((float4*)l1s)[i] = ((const float4*)l1)[i];
    __syncthreads();
    int n = blockIdx.x * 8 + nl;
    const float4* h4 = (const float4*)(h + (size_t)n * HIDN);
    float acc = 0.0f;
    #pragma unroll
    for (int k4 = 0; k4 < 32; ++k4) {
        float4 hv = h4[k4];
        acc = fmaf(hv.x, l1s[(k4 * 4 + 0) * NFT + f], acc);
        acc = fmaf(hv.y, l1s[(k4 * 4 + 1) * NFT + f], acc);
        acc = fmaf(hv.z, l1s[(k4 * 4 + 2) * NFT + f], acc);
        acc = fmaf(hv.w, l1s[(k4 * 4 + 3) * NFT + f], acc);
    }
    hw[(size_t)n * NFT + f] = acc;
}

// -------------------------------------------------- edge aggregate (CSR) ----
// One 64-lane wave per dst node: lane = (par, f); parity-split over edges
// (no intra-wave trip divergence), combined with shfl_xor(32). 2x unroll.
#define EDGE_BODY(EIDX)                                                    \
    {                                                                      \
        int e_ = (EIDX);                                                   \
        int s_ = src[e_];                                                  \
        float d_ = de[e_];                                                 \
        float cc_ = ce[e_];                                                \
        float p_ = d_ * TS;                                                \
        int i0_ = (int)p_;                                                 \
        i0_ = (i0_ > TABN - 2) ? (TABN - 2) : i0_;                         \
        float fr_ = p_ - (float)i0_;                                       \
        float w0_ = tabL[(size_t)i0_ * NFT + f];                           \
        float w1_ = tabL[(size_t)i0_ * NFT + NFT + f];                     \
        float w_ = fmaf(fr_, w1_ - w0_, w0_);                              \
        acc = fmaf(hw[(size_t)s_ * NFT + f], w_ * cc_, acc);               \
    }

__global__ void edge_agg(const int* __restrict__ rp, const int* __restrict__ src,
                         const float* __restrict__ de, const float* __restrict__ ce,
                         const float* __restrict__ tabL, const float* __restrict__ hw,
                         float* __restrict__ m) {
    int t = threadIdx.x;
    int f = t & 31, par = (t >> 5) & 1, g = t >> 6;   // 4 nodes / 256-thr block
    int n = blockIdx.x * 4 + g;
    int r0 = rp[n], r1 = rp[n + 1];
    const float TS = (TABN - 1) / CUTF;
    float acc = 0.0f;
    int e = r0 + par;
    for (; e + 2 < r1; e += 4) {          // two independent bodies -> ILP
        EDGE_BODY(e);
        EDGE_BODY(e + 2);
    }
    if (e < r1) EDGE_BODY(e);
    acc += __shfl_xor(acc, 32);
    if (par == 0) m[(size_t)n * NFT + f] = acc;
}

// --------------------------------- node update, MFMA (+ fused next-layer hw)
// x = ssp(m@l2w + l2b); h += x@lw + lb; hw_next = h_new @ l1[l+1]
// 256 threads = 4 waves; block owns 16 nodes; wave w owns f-tile pair
// {2w, 2w+1}. Grid NN/16 = 1024 blocks -> 4 blocks/CU, 16 waves/CU.
// ISSUE-EARLY: all global operands (m, weight frags, h rows, biases) loaded
// into named registers at entry so their latency overlaps once, not 14x.
// __launch_bounds__(256,4): VGPR cap 128 so they stay live (round-4 was
// squeezed to 48 VGPR -> serialized loads).
// mfma_f32_16x16x32_bf16 layouts (m89/m91-verified):
//   A: lane(16g+r) holds A[r][8g..8g+7];  B: lane(16g+c) holds B[8g..8g+7][c]
//   C/D: col = lane&15, row = 4*(lane>>4) + reg
// xs/hs tiles XOR-swizzled: 16B-granule ^= (row&7)  (G4).
__global__ __launch_bounds__(256, 4) void node_update_mfma(
        const float* __restrict__ mg, const short* __restrict__ l2wT,
        const float* __restrict__ l2b, const short* __restrict__ lwT,
        const float* __restrict__ lb, float* __restrict__ h,
        const short* __restrict__ l1Tn, float* __restrict__ hwn) {
    __shared__ short xs[16 * 128];          // 4 KB bf16, swizzled
    __shared__ short hs[16 * 128];          // 4 KB bf16, swizzled
    const int t   = threadIdx.x;
    const int w   = t >> 6;                 // wave 0..3
    const int l   = t & 63;
    const int lr  = l & 15;
    const int lg  = l >> 4;                 // k-group 0..3
    const int nb  = blockIdx.x << 4;        // 16 nodes per block
    const int ft0 = w * 2, ft1 = w * 2 + 1;

    // ======== issue-early: every global load this kernel needs ========
    const float* mrow = mg + (size_t)(nb + lr) * NFT + lg * 8;
    f32x4 m0 = *(const f32x4*)(mrow);
    f32x4 m1 = *(const f32x4*)(mrow + 4);
    bf16x8 aw0 = *(const bf16x8*)(l2wT + (ft0 * 16 + lr) * 32 + lg * 8);
    bf16x8 aw1 = *(const bf16x8*)(l2wT + (ft1 * 16 + lr) * 32 + lg * 8);
    bf16x8 bw0[4], bw1[4];
    #pragma unroll
    for (int ks = 0; ks < 4; ++ks) {
        bw0[ks] = *(const bf16x8*)(lwT + (ft0 * 16 + lr) * 128 + ks * 32 + lg * 8);
        bw1[ks] = *(const bf16x8*)(lwT + (ft1 * 16 + lr) * 128 + ks * 32 + lg * 8);
    }
    float hold0[4], hold1[4];
    #pragma unroll
    for (int i = 0; i < 4; ++i) {
        hold0[i] = h[(size_t)(nb + lg * 4 + i) * HIDN + ft0 * 16 + lr];
        hold1[i] = h[(size_t)(nb + lg * 4 + i) * HIDN + ft1 * 16 + lr];
    }
    float biasA0 = l2b[ft0 * 16 + lr], biasA1 = l2b[ft1 * 16 + lr];
    float biasB0 = lb[ft0 * 16 + lr],  biasB1 = lb[ft1 * 16 + lr];

    // ======== phase A: x = ssp(m @ l2w + l2b) ========
    bf16x8 ma;
    ma[0] = f2bf(m0.x); ma[1] = f2bf(m0.y); ma[2] = f2bf(m0.z); ma[3] = f2bf(m0.w);
    ma[4] = f2bf(m1.x); ma[5] = f2bf(m1.y); ma[6] = f2bf(m1.z); ma[7] = f2bf(m1.w);
    f32x4 cA0 = {0.f, 0.f, 0.f, 0.f}, cA1 = {0.f, 0.f, 0.f, 0.f};
    cA0 = __builtin_amdgcn_mfma_f32_16x16x32_bf16(ma, aw0, cA0, 0, 0, 0);
    cA1 = __builtin_amdgcn_mfma_f32_16x16x32_bf16(ma, aw1, cA1, 0, 0, 0);
    #pragma unroll
    for (int i = 0; i < 4; ++i) {
        int row = lg * 4 + i;
        int col0 = ft0 * 16 + lr;
        int col1 = ft1 * 16 + lr;
        xs[row * 128 + ((col0 >> 3) ^ (row & 7)) * 8 + (col0 & 7)] = f2bf(ssp(cA0[i] + biasA0));
        xs[row * 128 + ((col1 >> 3) ^ (row & 7)) * 8 + (col1 & 7)] = f2bf(ssp(cA1[i] + biasA1));
    }
    // issue phase-C weights while waiting at the barrier
    bf16x8 cw[4];
    if (l1Tn != nullptr && w < 2) {
        #pragma unroll
        for (int ks = 0; ks < 4; ++ks)
            cw[ks] = *(const bf16x8*)(l1Tn + (w * 16 + lr) * 128 + ks * 32 + lg * 8);
    }
    __syncthreads();

    // ======== phase B: h += x @ lw + lb  (K = 128) ========
    bf16x8 xa[4];
    #pragma unroll
    for (int ks = 0; ks < 4; ++ks)
        xa[ks] = *(const bf16x8*)(xs + lr * 128 + ((ks * 4 + lg) ^ (lr & 7)) * 8);
    f32x4 cB0 = {0.f, 0.f, 0.f, 0.f}, cB1 = {0.f, 0.f, 0.f, 0.f};
    #pragma unroll
    for (int ks = 0; ks < 4; ++ks)
        cB0 = __builtin_amdgcn_mfma_f32_16x16x32_bf16(xa[ks], bw0[ks], cB0, 0, 0, 0);
    #pragma unroll
    for (int ks = 0; ks < 4; ++ks)
        cB1 = __builtin_amdgcn_mfma_f32_16x16x32_bf16(xa[ks], bw1[ks], cB1, 0, 0, 0);
    #pragma unroll
    for (int i = 0; i < 4; ++i) {
        int node = nb + lg * 4 + i;
        int row = lg * 4 + i;
        float hv0 = hold0[i] + cB0[i] + biasB0;
        float hv1 = hold1[i] + cB1[i] + biasB1;
        h[(size_t)node * HIDN + ft0 * 16 + lr] = hv0;
        h[(size_t)node * HIDN + ft1 * 16 + lr] = hv1;
        int col0 = ft0 * 16 + lr;
        int col1 = ft1 * 16 + lr;
        hs[row * 128 + ((col0 >> 3) ^ (row & 7)) * 8 + (col0 & 7)] = f2bf(hv0);
        hs[row * 128 + ((col1 >> 3) ^ (row & 7)) * 8 + (col1 & 7)] = f2bf(hv1);
    }

    // ======== phase C: fused next-layer hw = h_new @ l1[l+1] ========
    if (l1Tn != nullptr) {
        __syncthreads();
        if (w < 2) {
            bf16x8 ha[4];
            #pragma unroll
            for (int ks = 0; ks < 4; ++ks)
                ha[ks] = *(const bf16x8*)(hs + lr * 128 + ((ks * 4 + lg) ^ (lr & 7)) * 8);
            f32x4 c = {0.f, 0.f, 0.f, 0.f};
            #pragma unroll
            for (int ks = 0; ks < 4; ++ks)
                c = __builtin_amdgcn_mfma_f32_16x16x32_bf16(ha[ks], cw[ks], c, 0, 0, 0);
            #pragma unroll
            for (int i = 0; i < 4; ++i) {
                int node = nb + lg * 4 + i;
                hwn[(size_t)node * NFT + w * 16 + lr] = c[i];
            }
        }
    }
}

// ---------------------------------------------------------------------------
extern "C" void kernel_launch(void* const* d_in, const int* in_sizes, int n_in,
                              void* d_out, int out_size, void* d_ws, size_t ws_size,
                              hipStream_t stream) {
    const int*   z    = (const int*)d_in[0];
    const float* pos  = (const float*)d_in[1];
    const int*   ei   = (const int*)d_in[2];    // [2][E]
    const float* mask = (const float*)d_in[3];
    const float* emb  = (const float*)d_in[4];
    const float* w1   = (const float*)d_in[5];  // [6][50][32]
    const float* b1   = (const float*)d_in[6];  // [6][32]
    const float* w2   = (const float*)d_in[7];  // [6][32][32]
    const float* b2   = (const float*)d_in[8];  // [6][32]
    const float* l1w  = (const float*)d_in[9];  // [6][128][32]
    const float* l2w  = (const float*)d_in[10]; // [6][32][128]
    const float* l2b  = (const float*)d_in[11]; // [6][128]
    const float* lww  = (const float*)d_in[12]; // [6][128][128]
    const float* lbb  = (const float*)d_in[13]; // [6][128]
    float* h = (float*)d_out;

    char* base = (char*)d_ws;
    size_t o = 0;
    auto alloc = [&](size_t bytes) -> void* {
        void* p = base + o;
        o += (bytes + 255) & ~(size_t)255;
        return p;
    };
    int*   d_rp   = (int*)alloc((NN + 1) * sizeof(int));
    float* d_de   = (float*)alloc((size_t)EE * sizeof(float));
    float* d_ce   = (float*)alloc((size_t)EE * sizeof(float));
    float* d_tab  = (float*)alloc((size_t)NLAY * TABN * NFT * sizeof(float));
    float* d_hw   = (float*)alloc((size_t)NN * NFT * sizeof(float));
    float* d_m    = (float*)alloc((size_t)NN * NFT * sizeof(float));
    short* d_l2wT = (short*)alloc((size_t)NLAY * 4096 * sizeof(short));
    short* d_lwT  = (short*)alloc((size_t)NLAY * 16384 * sizeof(short));
    short* d_l1T  = (short*)alloc((size_t)NLAY * 4096 * sizeof(short));
    (void)ws_size; (void)in_sizes; (void)n_in; (void)out_size;

    prep_weights<<<(NLAY * 24576 + 255) / 256, 256, 0, stream>>>(
        l2w, lww, l1w, d_l2wT, d_lwT, d_l1T);
    build_rowptr<<<(NN + 1 + 255) / 256, 256, 0, stream>>>(ei + EE, mask, d_rp);
    edge_geom<<<(EE + 255) / 256, 256, 0, stream>>>(ei, pos, mask, d_de, d_ce);
    tab_kernel<<<NLAY * TABN / 8, 256, 0, stream>>>(w1, b1, w2, b2, d_tab);
    init_h<<<NN * 32 / 256, 256, 0, stream>>>(z, (const float4*)emb, (float4*)h);
    hw_kernel<<<NN / 8, 256, 0, stream>>>(h, l1w, d_hw);   // layer-0 hw (f32)

    for (int l = 0; l < NLAY; ++l) {
        edge_agg<<<NN / 4, 256, 0, stream>>>(d_rp, ei, d_de, d_ce,
                                             d_tab + (size_t)l * TABN * NFT, d_hw, d_m);
        const short* l1Tn = (l + 1 < NLAY) ? (d_l1T + (size_t)(l + 1) * 4096) : nullptr;
        node_update_mfma<<<NN / 16, 256, 0, stream>>>(
            d_m, d_l2wT + (size_t)l * 4096, l2b + (size_t)l * HIDN,
            d_lwT + (size_t)l * 16384, lbb + (size_t)l * HIDN, h, l1Tn, d_hw);
    }
}